// Round 2
// baseline (95906.836 us; speedup 1.0000x reference)
//
#include <hip/hip_runtime.h>
#include <hip/hip_fp16.h>
#include <math.h>

#define HH 512
#define BB 128
#define SS 1024
#define TT 128
#define VV 32
#define GG 1536

__device__ __forceinline__ float sigm(float v){ return 1.f/(1.f+expf(-v)); }

struct F8 { float v[8]; };

__device__ __forceinline__ F8 load8(const float* p){
  F8 r;
  float4 a = *reinterpret_cast<const float4*>(p);
  float4 b = *reinterpret_cast<const float4*>(p+4);
  r.v[0]=a.x; r.v[1]=a.y; r.v[2]=a.z; r.v[3]=a.w;
  r.v[4]=b.x; r.v[5]=b.y; r.v[6]=b.z; r.v[7]=b.w;
  return r;
}
__device__ __forceinline__ F8 load8(const __half* p){
  F8 r;
  union { float4 f4; __half2 h2[4]; } u;
  u.f4 = *reinterpret_cast<const float4*>(p);
  #pragma unroll
  for (int i=0;i<4;i++){ float2 f = __half22float2(u.h2[i]); r.v[2*i]=f.x; r.v[2*i+1]=f.y; }
  return r;
}
__device__ __forceinline__ void store_enc(float* p, float v){ *p = v; }
__device__ __forceinline__ void store_enc(__half* p, float v){ *p = __float2half(v); }

// ---------- generic transpose: src[R][C] -> dst[C][R] ----------
__global__ void transpose_k(const float* __restrict__ src, float* __restrict__ dst,
                            int R, int C){
  __shared__ float tile[32][33];
  int c0 = blockIdx.x*32, r0 = blockIdx.y*32;
  int tx = threadIdx.x & 31, ty = threadIdx.x >> 5;  // 32 x 8
  for (int i = ty; i < 32; i += 8){
    int r = r0 + i, c = c0 + tx;
    tile[i][tx] = (r < R && c < C) ? src[(size_t)r*C + c] : 0.f;
  }
  __syncthreads();
  for (int i = ty; i < 32; i += 8){
    int c = c0 + i, r = r0 + tx;
    if (c < C && r < R) dst[(size_t)c*R + r] = tile[tx][i];
  }
}

// ---------- encoder pipeline step ----------
// pipeline index p in [0,1024]; layer0 computes step p (if p<1024),
// layer1 computes step p-1 (if p>=1).
template<typename ET>
__global__ __launch_bounds__(192) void enc_step(
    int p,
    const float* __restrict__ x,
    const float* __restrict__ Wih0,
    const float* __restrict__ bih0, const float* __restrict__ bhh0,
    const float* __restrict__ bih1, const float* __restrict__ bhh1,
    const float* __restrict__ Whh0T, const float* __restrict__ Wih1T,
    const float* __restrict__ Whh1T,
    float* __restrict__ gh_all,   // [2][3][BB][GG]
    float* __restrict__ h0buf,    // [2][BB][HH]
    float* __restrict__ h1buf,    // [2][BB][HH]
    ET* __restrict__ out_enc)     // [BB][SS][HH]
{
  const int bid = blockIdx.x;
  const int xcd = bid & 7, j = bid >> 3;      // j in [0,48)
  const int rc  = xcd*3 + (j % 3);            // [0,24)
  const int bch = j / 3;                      // [0,16)
  const int m   = rc >> 3;                    // 0..2
  const int pb  = p & 1;
  if (m == 0 && p >= SS) return;
  if (m >= 1 && p < 1) return;
  const int b0 = bch*8;
  const int tid = threadIdx.x;

  if (m <= 1) {
    float* h0w = h0buf + (size_t)pb*BB*HH;
    for (int idx = tid; idx < 8*HH; idx += 192) {
      int bl = idx >> 9, e = idx & (HH-1);
      int b = b0 + bl;
      float hv;
      if (p == 0) hv = 0.f;
      else {
        int t0 = p - 1;
        float x0v = x[((size_t)b*SS + t0)*2 + 0];
        float x1v = x[((size_t)b*SS + t0)*2 + 1];
        const float* ghp = gh_all + ((size_t)(1-pb)*3 + 0)*BB*GG + (size_t)b*GG;
        float gir = fmaf(x0v, Wih0[e*2],          fmaf(x1v, Wih0[e*2+1],          bih0[e]));
        float giz = fmaf(x0v, Wih0[(HH+e)*2],     fmaf(x1v, Wih0[(HH+e)*2+1],     bih0[HH+e]));
        float gin = fmaf(x0v, Wih0[(2*HH+e)*2],   fmaf(x1v, Wih0[(2*HH+e)*2+1],   bih0[2*HH+e]));
        float ghr = ghp[e]      + bhh0[e];
        float ghz = ghp[HH+e]   + bhh0[HH+e];
        float ghn = ghp[2*HH+e] + bhh0[2*HH+e];
        float hp = (p == 1) ? 0.f : h0buf[(size_t)(1-pb)*BB*HH + (size_t)b*HH + e];
        float r = sigm(gir + ghr);
        float z = sigm(giz + ghz);
        float n = tanhf(fmaf(r, ghn, gin));
        hv = (1.f - z)*n + z*hp;
      }
      h0w[(size_t)b*HH + e] = hv;
    }
  } else {
    float* h1w = h1buf + (size_t)pb*BB*HH;
    for (int idx = tid; idx < 8*HH; idx += 192) {
      int bl = idx >> 9, e = idx & (HH-1);
      int b = b0 + bl;
      float hv;
      if (p <= 1) hv = 0.f;
      else {
        const float* gip = gh_all + ((size_t)(1-pb)*3 + 1)*BB*GG + (size_t)b*GG;
        const float* ghp = gh_all + ((size_t)(1-pb)*3 + 2)*BB*GG + (size_t)b*GG;
        float gir = gip[e]      + bih1[e];
        float giz = gip[HH+e]   + bih1[HH+e];
        float gin = gip[2*HH+e] + bih1[2*HH+e];
        float ghr = ghp[e]      + bhh1[e];
        float ghz = ghp[HH+e]   + bhh1[HH+e];
        float ghn = ghp[2*HH+e] + bhh1[2*HH+e];
        float hp = (p == 2) ? 0.f : h1buf[(size_t)(1-pb)*BB*HH + (size_t)b*HH + e];
        float r = sigm(gir + ghr);
        float z = sigm(giz + ghz);
        float n = tanhf(fmaf(r, ghn, gin));
        hv = (1.f - z)*n + z*hp;
      }
      h1w[(size_t)b*HH + e] = hv;
      if (p >= 2) store_enc(out_enc + ((size_t)b*SS + (p-2))*HH + e, hv);
    }
  }
  __syncthreads();

  const float* WT   = (m == 0) ? Whh0T : (m == 1) ? Wih1T : Whh1T;
  const float* hsrc = (m == 2) ? (h1buf + (size_t)pb*BB*HH) : (h0buf + (size_t)pb*BB*HH);
  const int wv = tid >> 6, lane = tid & 63;
  const int row = (rc & 7)*192 + wv*64 + lane;
  const float* wcol = WT + row;
  float acc[8] = {0,0,0,0,0,0,0,0};
  for (int k = 0; k < HH; k += 4) {
    float w0 = wcol[(size_t)(k+0)*GG];
    float w1 = wcol[(size_t)(k+1)*GG];
    float w2 = wcol[(size_t)(k+2)*GG];
    float w3 = wcol[(size_t)(k+3)*GG];
    #pragma unroll
    for (int i = 0; i < 8; i++) {
      const float4 h4 = *reinterpret_cast<const float4*>(hsrc + (size_t)(b0+i)*HH + k);
      acc[i] = fmaf(w3, h4.w, fmaf(w2, h4.z, fmaf(w1, h4.y, fmaf(w0, h4.x, acc[i]))));
    }
  }
  float* dst = gh_all + ((size_t)pb*3 + m)*BB*GG;
  #pragma unroll
  for (int i = 0; i < 8; i++) dst[(size_t)(b0+i)*GG + row] = acc[i];
}

// ---------- bridge: finalize h1 state after encoder step 1023 ----------
template<typename ET>
__global__ void enc_bridge(
    const float* __restrict__ gh_all, const float* __restrict__ h1buf,
    const float* __restrict__ bih1, const float* __restrict__ bhh1,
    float* __restrict__ h1init, ET* __restrict__ out_enc)
{
  int idx = blockIdx.x*256 + threadIdx.x;   // 65536 total
  int b = idx >> 9, e = idx & (HH-1);
  const float* gip = gh_all + (size_t)1*BB*GG + (size_t)b*GG;  // pb=0 slot m1
  const float* ghp = gh_all + (size_t)2*BB*GG + (size_t)b*GG;  // pb=0 slot m2
  float gir = gip[e]      + bih1[e];
  float giz = gip[HH+e]   + bih1[HH+e];
  float gin = gip[2*HH+e] + bih1[2*HH+e];
  float ghr = ghp[e]      + bhh1[e];
  float ghz = ghp[HH+e]   + bhh1[HH+e];
  float ghn = ghp[2*HH+e] + bhh1[2*HH+e];
  float hp = h1buf[(size_t)b*HH + e];   // h1 after step 1022 (pb=0 half)
  float r = sigm(gir + ghr);
  float z = sigm(giz + ghz);
  float n = tanhf(fmaf(r, ghn, gin));
  float hv = (1.f - z)*n + z*hp;
  h1init[(size_t)b*HH + e] = hv;
  store_enc(out_enc + ((size_t)b*SS + (SS-1))*HH + e, hv);
}

// ---------- decoder cell0 dots ----------
__global__ __launch_bounds__(192) void dec_step1(
    int t,
    const float* __restrict__ embedding,
    const int* __restrict__ tok,
    const float* __restrict__ bih0d, const float* __restrict__ bhh0d,
    const float* __restrict__ Wih0T, const float* __restrict__ Whh0T,
    const float* __restrict__ h0init,
    float* __restrict__ dgh0,     // [2][2][BB][GG]
    float* __restrict__ h0d)      // [2][BB][HH]
{
  const int bid = blockIdx.x;
  const int xcd = bid & 7, j = bid >> 3;   // j in [0,32)
  const int rc  = xcd*2 + (j & 1);         // [0,16)
  const int bch = j >> 1;                  // [0,16)
  const int m   = rc >> 3;                 // 0: Wih0*emb, 1: Whh0*h0s
  const int db  = t & 1;
  const int b0 = bch*8;
  const int tid = threadIdx.x;

  if (m == 1) {
    float* hw = h0d + (size_t)db*BB*HH;
    for (int idx = tid; idx < 8*HH; idx += 192) {
      int bl = idx >> 9, e = idx & (HH-1);
      int b = b0 + bl;
      float hv;
      if (t == 0) hv = h0init[(size_t)b*HH + e];
      else {
        const float* gip = dgh0 + ((size_t)(1-db)*2 + 0)*BB*GG + (size_t)b*GG;
        const float* ghp = dgh0 + ((size_t)(1-db)*2 + 1)*BB*GG + (size_t)b*GG;
        float gir = gip[e]      + bih0d[e];
        float giz = gip[HH+e]   + bih0d[HH+e];
        float gin = gip[2*HH+e] + bih0d[2*HH+e];
        float ghr = ghp[e]      + bhh0d[e];
        float ghz = ghp[HH+e]   + bhh0d[HH+e];
        float ghn = ghp[2*HH+e] + bhh0d[2*HH+e];
        float hp = (t == 1) ? h0init[(size_t)b*HH + e]
                            : h0d[(size_t)(1-db)*BB*HH + (size_t)b*HH + e];
        float r = sigm(gir + ghr);
        float z = sigm(giz + ghz);
        float n = tanhf(fmaf(r, ghn, gin));
        hv = (1.f - z)*n + z*hp;
      }
      hw[(size_t)b*HH + e] = hv;
    }
  }
  __syncthreads();

  const float* WT = (m == 0) ? Wih0T : Whh0T;
  const int wv = tid >> 6, lane = tid & 63;
  const int row = (rc & 7)*192 + wv*64 + lane;
  const float* wcol = WT + row;
  const float* hp8[8];
  #pragma unroll
  for (int i = 0; i < 8; i++)
    hp8[i] = (m == 0) ? (embedding + (size_t)tok[b0+i]*HH)
                      : (h0d + (size_t)db*BB*HH + (size_t)(b0+i)*HH);
  float acc[8] = {0,0,0,0,0,0,0,0};
  for (int k = 0; k < HH; k += 4) {
    float w0 = wcol[(size_t)(k+0)*GG];
    float w1 = wcol[(size_t)(k+1)*GG];
    float w2 = wcol[(size_t)(k+2)*GG];
    float w3 = wcol[(size_t)(k+3)*GG];
    #pragma unroll
    for (int i = 0; i < 8; i++) {
      const float4 h4 = *reinterpret_cast<const float4*>(hp8[i] + k);
      acc[i] = fmaf(w3, h4.w, fmaf(w2, h4.z, fmaf(w1, h4.y, fmaf(w0, h4.x, acc[i]))));
    }
  }
  float* dst = dgh0 + ((size_t)db*2 + m)*BB*GG;
  #pragma unroll
  for (int i = 0; i < 8; i++) dst[(size_t)(b0+i)*GG + row] = acc[i];
}

// ---------- decoder cell1 dots ----------
__global__ __launch_bounds__(192) void dec_step2(
    int t,
    const float* __restrict__ bih0d, const float* __restrict__ bhh0d,
    const float* __restrict__ bih1d, const float* __restrict__ bhh1d,
    const float* __restrict__ Wih1T, const float* __restrict__ Whh1T,
    const float* __restrict__ h1init,
    const float* __restrict__ dgh0,
    const float* __restrict__ h0d,
    float* __restrict__ dgh1,     // [2][2][BB][GG]
    float* __restrict__ h1d,      // [2][BB][HH]
    float* __restrict__ h0n)      // [BB][HH]
{
  const int bid = blockIdx.x;
  const int xcd = bid & 7, j = bid >> 3;
  const int rc  = xcd*2 + (j & 1);
  const int bch = j >> 1;
  const int m   = rc >> 3;                 // 0: Wih1*h0n, 1: Whh1*h1s
  const int db  = t & 1;
  const int b0 = bch*8;
  const int tid = threadIdx.x;

  if (m == 0) {
    for (int idx = tid; idx < 8*HH; idx += 192) {
      int bl = idx >> 9, e = idx & (HH-1);
      int b = b0 + bl;
      const float* gip = dgh0 + ((size_t)db*2 + 0)*BB*GG + (size_t)b*GG;
      const float* ghp = dgh0 + ((size_t)db*2 + 1)*BB*GG + (size_t)b*GG;
      float gir = gip[e]      + bih0d[e];
      float giz = gip[HH+e]   + bih0d[HH+e];
      float gin = gip[2*HH+e] + bih0d[2*HH+e];
      float ghr = ghp[e]      + bhh0d[e];
      float ghz = ghp[HH+e]   + bhh0d[HH+e];
      float ghn = ghp[2*HH+e] + bhh0d[2*HH+e];
      float hp = h0d[(size_t)db*BB*HH + (size_t)b*HH + e];
      float r = sigm(gir + ghr);
      float z = sigm(giz + ghz);
      float n = tanhf(fmaf(r, ghn, gin));
      h0n[(size_t)b*HH + e] = (1.f - z)*n + z*hp;
    }
  } else {
    float* hw = h1d + (size_t)db*BB*HH;
    for (int idx = tid; idx < 8*HH; idx += 192) {
      int bl = idx >> 9, e = idx & (HH-1);
      int b = b0 + bl;
      float hv;
      if (t == 0) hv = h1init[(size_t)b*HH + e];
      else {
        const float* gip = dgh1 + ((size_t)(1-db)*2 + 0)*BB*GG + (size_t)b*GG;
        const float* ghp = dgh1 + ((size_t)(1-db)*2 + 1)*BB*GG + (size_t)b*GG;
        float gir = gip[e]      + bih1d[e];
        float giz = gip[HH+e]   + bih1d[HH+e];
        float gin = gip[2*HH+e] + bih1d[2*HH+e];
        float ghr = ghp[e]      + bhh1d[e];
        float ghz = ghp[HH+e]   + bhh1d[HH+e];
        float ghn = ghp[2*HH+e] + bhh1d[2*HH+e];
        float hp = (t == 1) ? h1init[(size_t)b*HH + e]
                            : h1d[(size_t)(1-db)*BB*HH + (size_t)b*HH + e];
        float r = sigm(gir + ghr);
        float z = sigm(giz + ghz);
        float n = tanhf(fmaf(r, ghn, gin));
        hv = (1.f - z)*n + z*hp;
      }
      hw[(size_t)b*HH + e] = hv;
    }
  }
  __syncthreads();

  const float* WT = (m == 0) ? Wih1T : Whh1T;
  const float* hsrc = (m == 0) ? h0n : (h1d + (size_t)db*BB*HH);
  const int wv = tid >> 6, lane = tid & 63;
  const int row = (rc & 7)*192 + wv*64 + lane;
  const float* wcol = WT + row;
  float acc[8] = {0,0,0,0,0,0,0,0};
  for (int k = 0; k < HH; k += 4) {
    float w0 = wcol[(size_t)(k+0)*GG];
    float w1 = wcol[(size_t)(k+1)*GG];
    float w2 = wcol[(size_t)(k+2)*GG];
    float w3 = wcol[(size_t)(k+3)*GG];
    #pragma unroll
    for (int i = 0; i < 8; i++) {
      const float4 h4 = *reinterpret_cast<const float4*>(hsrc + (size_t)(b0+i)*HH + k);
      acc[i] = fmaf(w3, h4.w, fmaf(w2, h4.z, fmaf(w1, h4.y, fmaf(w0, h4.x, acc[i]))));
    }
  }
  float* dst = dgh1 + ((size_t)db*2 + m)*BB*GG;
  #pragma unroll
  for (int i = 0; i < 8; i++) dst[(size_t)(b0+i)*GG + row] = acc[i];
}

// ---------- decoder: finalize h1n, compute q ----------
__global__ __launch_bounds__(256) void dec_step3(
    int t,
    const float* __restrict__ bih1d, const float* __restrict__ bhh1d,
    const float* __restrict__ WqT, const float* __restrict__ bq,
    const float* __restrict__ dgh1, const float* __restrict__ h1d,
    float* __restrict__ h1n, float* __restrict__ qbuf)
{
  const int rc = blockIdx.x & 1, bch = blockIdx.x >> 1;   // 2 x 16
  const int db = t & 1, b0 = bch*8, tid = threadIdx.x;
  for (int idx = tid; idx < 8*HH; idx += 256) {
    int bl = idx >> 9, e = idx & (HH-1);
    int b = b0 + bl;
    const float* gip = dgh1 + ((size_t)db*2 + 0)*BB*GG + (size_t)b*GG;
    const float* ghp = dgh1 + ((size_t)db*2 + 1)*BB*GG + (size_t)b*GG;
    float gir = gip[e]      + bih1d[e];
    float giz = gip[HH+e]   + bih1d[HH+e];
    float gin = gip[2*HH+e] + bih1d[2*HH+e];
    float ghr = ghp[e]      + bhh1d[e];
    float ghz = ghp[HH+e]   + bhh1d[HH+e];
    float ghn = ghp[2*HH+e] + bhh1d[2*HH+e];
    float hp = h1d[(size_t)db*BB*HH + (size_t)b*HH + e];
    float r = sigm(gir + ghr);
    float z = sigm(giz + ghz);
    float n = tanhf(fmaf(r, ghn, gin));
    h1n[(size_t)b*HH + e] = (1.f - z)*n + z*hp;
  }
  __syncthreads();
  const int wv = tid >> 6, lane = tid & 63;
  const int row = rc*256 + wv*64 + lane;   // [0,512)
  const float* wcol = WqT + row;
  float acc[8] = {0,0,0,0,0,0,0,0};
  for (int k = 0; k < HH; k += 4) {
    float w0 = wcol[(size_t)(k+0)*HH];
    float w1 = wcol[(size_t)(k+1)*HH];
    float w2 = wcol[(size_t)(k+2)*HH];
    float w3 = wcol[(size_t)(k+3)*HH];
    #pragma unroll
    for (int i = 0; i < 8; i++) {
      const float4 h4 = *reinterpret_cast<const float4*>(h1n + (size_t)(b0+i)*HH + k);
      acc[i] = fmaf(w3, h4.w, fmaf(w2, h4.z, fmaf(w1, h4.y, fmaf(w0, h4.x, acc[i]))));
    }
  }
  #pragma unroll
  for (int i = 0; i < 8; i++) qbuf[(size_t)(b0+i)*HH + row] = acc[i] + bq[row];
}

// ---------- decoder: one-pass attention with online softmax ----------
template<typename ET>
__global__ __launch_bounds__(256) void dec_attn(
    const float* __restrict__ qbuf, const ET* __restrict__ out_enc,
    float* __restrict__ att, float* __restrict__ pm, float* __restrict__ pl,
    float* __restrict__ pctx)
{
  const int b = blockIdx.x >> 3, sc = blockIdx.x & 7;
  const int tid = threadIdx.x, wv = tid >> 6, lane = tid & 63;
  const F8 q = load8(qbuf + (size_t)b*HH + lane*8);
  const ET* encb = out_enc + (size_t)b*SS*HH;
  float mrun = -1e30f, lrun = 0.f;
  float c[8] = {0,0,0,0,0,0,0,0};
  float attkeep = 0.f;
  const int sbase = sc*128 + wv*32;
  for (int ii = 0; ii < 32; ii++) {
    const F8 e = load8(encb + (size_t)(sbase + ii)*HH + lane*8);
    float d = 0.f;
    #pragma unroll
    for (int j = 0; j < 8; j++) d = fmaf(q.v[j], e.v[j], d);
    #pragma unroll
    for (int off = 32; off >= 1; off >>= 1) d += __shfl_xor(d, off, 64);
    if (lane == ii) attkeep = d;
    float mnew = fmaxf(mrun, d);
    float scal = expf(mrun - mnew);
    float pv = expf(d - mnew);
    lrun = fmaf(lrun, scal, pv);
    #pragma unroll
    for (int j = 0; j < 8; j++) c[j] = fmaf(c[j], scal, pv*e.v[j]);
    mrun = mnew;
  }
  if (lane < 32) att[(size_t)b*SS + sbase + lane] = attkeep;
  __shared__ float lm[4], ll[4];
  __shared__ float lctx[4][HH];
  if (lane == 0) { lm[wv] = mrun; ll[wv] = lrun; }
  #pragma unroll
  for (int j = 0; j < 8; j++) lctx[wv][lane*8+j] = c[j];
  __syncthreads();
  float mb = fmaxf(fmaxf(lm[0],lm[1]), fmaxf(lm[2],lm[3]));
  float e0w = expf(lm[0]-mb), e1w = expf(lm[1]-mb), e2w = expf(lm[2]-mb), e3w = expf(lm[3]-mb);
  if (tid == 0) {
    pm[b*8+sc] = mb;
    pl[b*8+sc] = e0w*ll[0] + e1w*ll[1] + e2w*ll[2] + e3w*ll[3];
  }
  for (int k2 = tid; k2 < HH; k2 += 256) {
    float s = e0w*lctx[0][k2] + e1w*lctx[1][k2] + e2w*lctx[2][k2] + e3w*lctx[3][k2];
    pctx[((size_t)b*8 + sc)*HH + k2] = s;
  }
}

// ---------- decoder: combine partials, attn weights out, logits, argmax ----------
__global__ __launch_bounds__(256) void dec_final(
    int t,
    const float* __restrict__ pm, const float* __restrict__ pl,
    const float* __restrict__ pctx, const float* __restrict__ att,
    const float* __restrict__ h1n,
    const float* __restrict__ WcT, const float* __restrict__ bc,
    float* __restrict__ out_vec, float* __restrict__ out_attn,
    int* __restrict__ tok)
{
  const int b = blockIdx.x, tid = threadIdx.x;
  __shared__ float s_hc[2*HH];
  __shared__ float s_red[8][33];
  float pmv[8], plv[8];
  #pragma unroll
  for (int c = 0; c < 8; c++){ pmv[c] = pm[b*8+c]; plv[c] = pl[b*8+c]; }
  float mg = pmv[0];
  #pragma unroll
  for (int c = 1; c < 8; c++) mg = fmaxf(mg, pmv[c]);
  float epm[8]; float lg = 0.f;
  #pragma unroll
  for (int c = 0; c < 8; c++){ epm[c] = expf(pmv[c]-mg); lg += epm[c]*plv[c]; }
  float inv_lg = 1.f/lg;
  for (int k = tid; k < HH; k += 256) {
    float s = 0.f;
    #pragma unroll
    for (int c = 0; c < 8; c++) s += epm[c]*pctx[((size_t)b*8+c)*HH + k];
    s_hc[HH + k] = s * inv_lg;
    s_hc[k] = h1n[(size_t)b*HH + k];
  }
  __syncthreads();
  for (int s = tid; s < SS; s += 256)
    out_attn[((size_t)b*SS + s)*TT + t] = expf(att[(size_t)b*SS + s] - mg) * inv_lg;
  const int v = tid & 31, part = tid >> 5;
  float pacc = 0.f;
  for (int k = part*128; k < part*128 + 128; k++)
    pacc = fmaf(s_hc[k], WcT[(size_t)k*VV + v], pacc);
  s_red[part][v] = pacc;
  __syncthreads();
  if (tid < 32) {
    float lv = bc[tid];
    #pragma unroll
    for (int c = 0; c < 8; c++) lv += s_red[c][tid];
    out_vec[((size_t)b*TT + t)*VV + tid] = lv;
    float bv = lv; int bi = tid;
    #pragma unroll
    for (int off = 16; off >= 1; off >>= 1) {
      float ov = __shfl_xor(bv, off, 64);
      int   oi = __shfl_xor(bi, off, 64);
      if (ov > bv || (ov == bv && oi < bi)) { bv = ov; bi = oi; }
    }
    if (tid == 0) tok[b] = bi;
  }
}

// ---------- host-side buffer bundle ----------
struct Bufs {
  const float *x, *emb;
  const float *eWih0, *ebih0, *ebhh0, *ebih1, *ebhh1;
  const float *dbih0, *dbhh0, *dbih1, *dbhh1, *bq, *bc;
  float *gh_all, *dgh0, *dgh1;
  float *h0buf, *h1buf, *h0d, *h1d, *h0n, *h1n, *h1init, *qbuf;
  float *att, *pmb, *plb, *pctx;
  int   *tok;
  float *Whh0T, *Wih1T, *Whh1T, *dWih0T, *dWhh0T, *dWih1T, *dWhh1T, *WqT, *WcT;
  float *out_vec, *out_hid, *out_attn;
};

template<typename ET>
static void run_pipeline(const Bufs& B, ET* out_enc, hipStream_t stream) {
  hipMemsetAsync(B.tok, 0, BB*sizeof(int), stream);
  for (int p = 0; p <= SS; p++)
    enc_step<ET><<<dim3(384), dim3(192), 0, stream>>>(p,
        B.x, B.eWih0, B.ebih0, B.ebhh0, B.ebih1, B.ebhh1,
        B.Whh0T, B.Wih1T, B.Whh1T,
        B.gh_all, B.h0buf, B.h1buf, out_enc);
  enc_bridge<ET><<<dim3(256), dim3(256), 0, stream>>>(
      B.gh_all, B.h1buf, B.ebih1, B.ebhh1, B.h1init, out_enc);
  const float* h0init = B.h0buf;   // half 0 holds h0 state after step 1023

  for (int t = 0; t < TT; t++) {
    dec_step1<<<dim3(256), dim3(192), 0, stream>>>(t,
        B.emb, B.tok, B.dbih0, B.dbhh0, B.dWih0T, B.dWhh0T, h0init, B.dgh0, B.h0d);
    dec_step2<<<dim3(256), dim3(192), 0, stream>>>(t,
        B.dbih0, B.dbhh0, B.dbih1, B.dbhh1, B.dWih1T, B.dWhh1T, B.h1init,
        B.dgh0, B.h0d, B.dgh1, B.h1d, B.h0n);
    dec_step3<<<dim3(32), dim3(256), 0, stream>>>(t,
        B.dbih1, B.dbhh1, B.WqT, B.bq, B.dgh1, B.h1d, B.h1n, B.qbuf);
    dec_attn<ET><<<dim3(1024), dim3(256), 0, stream>>>(
        B.qbuf, out_enc, B.att, B.pmb, B.plb, B.pctx);
    dec_final<<<dim3(128), dim3(256), 0, stream>>>(t,
        B.pmb, B.plb, B.pctx, B.att, B.h1n, B.WcT, B.bc,
        B.out_vec, B.out_attn, B.tok);
  }
  hipMemcpyAsync(B.out_hid, B.h0n, (size_t)BB*HH*sizeof(float),
                 hipMemcpyDeviceToDevice, stream);
  hipMemcpyAsync(B.out_hid + (size_t)BB*HH, B.h1n, (size_t)BB*HH*sizeof(float),
                 hipMemcpyDeviceToDevice, stream);
}

extern "C" void kernel_launch(void* const* d_in, const int* in_sizes, int n_in,
                              void* d_out, int out_size, void* d_ws, size_t ws_size,
                              hipStream_t stream) {
  const float* x      = (const float*)d_in[0];
  const float* emb    = (const float*)d_in[1];
  const float* eWih0  = (const float*)d_in[2];
  const float* eWhh0  = (const float*)d_in[3];
  const float* ebih0  = (const float*)d_in[4];
  const float* ebhh0  = (const float*)d_in[5];
  const float* eWih1  = (const float*)d_in[6];
  const float* eWhh1  = (const float*)d_in[7];
  const float* ebih1  = (const float*)d_in[8];
  const float* ebhh1  = (const float*)d_in[9];
  const float* dWih0  = (const float*)d_in[10];
  const float* dWhh0  = (const float*)d_in[11];
  const float* dbih0  = (const float*)d_in[12];
  const float* dbhh0  = (const float*)d_in[13];
  const float* dWih1  = (const float*)d_in[14];
  const float* dWhh1  = (const float*)d_in[15];
  const float* dbih1  = (const float*)d_in[16];
  const float* dbhh1  = (const float*)d_in[17];
  const float* Wq     = (const float*)d_in[18];
  const float* bq     = (const float*)d_in[19];
  const float* Wc     = (const float*)d_in[20];
  const float* bc     = (const float*)d_in[21];
  (void)in_sizes; (void)n_in; (void)out_size;

  float* ws = (float*)d_ws;
  size_t off = 0;
  auto alloc = [&](size_t n){ float* p = ws + off; off += n; return p; };

  Bufs B;
  B.x = x; B.emb = emb;
  B.eWih0 = eWih0; B.ebih0 = ebih0; B.ebhh0 = ebhh0; B.ebih1 = ebih1; B.ebhh1 = ebhh1;
  B.dbih0 = dbih0; B.dbhh0 = dbhh0; B.dbih1 = dbih1; B.dbhh1 = dbhh1;
  B.bq = bq; B.bc = bc;

  B.gh_all  = alloc((size_t)2*3*BB*GG);
  B.dgh0    = alloc((size_t)2*2*BB*GG);
  B.dgh1    = alloc((size_t)2*2*BB*GG);
  B.h0buf   = alloc((size_t)2*BB*HH);
  B.h1buf   = alloc((size_t)2*BB*HH);
  B.h0d     = alloc((size_t)2*BB*HH);
  B.h1d     = alloc((size_t)2*BB*HH);
  B.h0n     = alloc((size_t)BB*HH);
  B.h1n     = alloc((size_t)BB*HH);
  B.h1init  = alloc((size_t)BB*HH);
  B.qbuf    = alloc((size_t)BB*HH);
  B.att     = alloc((size_t)BB*SS);
  B.pmb     = alloc((size_t)BB*8);
  B.plb     = alloc((size_t)BB*8);
  B.pctx    = alloc((size_t)BB*8*HH);
  B.tok     = (int*)alloc((size_t)BB);
  B.Whh0T   = alloc((size_t)HH*GG);
  B.Wih1T   = alloc((size_t)HH*GG);
  B.Whh1T   = alloc((size_t)HH*GG);
  B.dWih0T  = alloc((size_t)HH*GG);
  B.dWhh0T  = alloc((size_t)HH*GG);
  B.dWih1T  = alloc((size_t)HH*GG);
  B.dWhh1T  = alloc((size_t)HH*GG);
  B.WqT     = alloc((size_t)HH*HH);
  B.WcT     = alloc((size_t)2*HH*VV);

  B.out_vec  = (float*)d_out;
  B.out_hid  = (float*)d_out + (size_t)BB*TT*VV;
  B.out_attn = (float*)d_out + (size_t)BB*TT*VV + (size_t)2*BB*HH;

  dim3 tb(256);
  transpose_k<<<dim3(16,48), tb, 0, stream>>>(eWhh0, B.Whh0T, GG, HH);
  transpose_k<<<dim3(16,48), tb, 0, stream>>>(eWih1, B.Wih1T, GG, HH);
  transpose_k<<<dim3(16,48), tb, 0, stream>>>(eWhh1, B.Whh1T, GG, HH);
  transpose_k<<<dim3(16,48), tb, 0, stream>>>(dWih0, B.dWih0T, GG, HH);
  transpose_k<<<dim3(16,48), tb, 0, stream>>>(dWhh0, B.dWhh0T, GG, HH);
  transpose_k<<<dim3(16,48), tb, 0, stream>>>(dWih1, B.dWih1T, GG, HH);
  transpose_k<<<dim3(16,48), tb, 0, stream>>>(dWhh1, B.dWhh1T, GG, HH);
  transpose_k<<<dim3(16,16), tb, 0, stream>>>(Wq, B.WqT, HH, HH);
  transpose_k<<<dim3(32,1),  tb, 0, stream>>>(Wc, B.WcT, VV, 2*HH);

  // out_enc takes the remainder of the workspace: fp32 if it fits, else fp16.
  const size_t enc_elems = (size_t)BB*SS*HH;
  const size_t need32 = (off + enc_elems) * sizeof(float);
  if (ws_size >= need32) {
    float* out_enc = ws + off;
    run_pipeline<float>(B, out_enc, stream);
  } else {
    __half* out_enc = reinterpret_cast<__half*>(ws + off);
    run_pipeline<__half>(B, out_enc, stream);
  }
}